// Round 1
// baseline (118.440 us; speedup 1.0000x reference)
//
#include <hip/hip_runtime.h>

#define N_ROWS 8192   // inputs rows (n)
#define K_CENT 1024   // centers rows (m)
#define DIM    1024   // d (elements; == bytes in fp8)

#define NKB   (DIM / 128)   // 8 k-blocks of 128 fp8 bytes per row
#define TILEB 2048          // bytes per fragment tile: 16 rows x 128 k

typedef __attribute__((ext_vector_type(4))) float f32x4;
typedef __attribute__((ext_vector_type(8))) int   i32x8;

// Fragment-order layout for v_mfma_scale_f32_16x16x128_f8f6f4:
//   matrix = [row_tile rt][k_block kb] tiles of 2048 B
//   within a tile, the 32 B chunk for (row r in 0..15, quad q in 0..3)
//   lives at r*128 + q*32  (lane l reads its 32 B at (l&15)*128 + (l>>4)*32)

// ---- kernel 1: fp32 -> fp8 e4m3 (scale 2^0), fragment-order store, exact norms ----
// one wave per row; lane handles 16 contiguous elems (64 B read, 16 B write).
// frag-order dst for k = lane*16..+15:
//   kb = lane>>3, quad = (lane>>1)&3, byte-in-quad = (lane&1)*16
// => each 8-lane group writes one full contiguous 128 B line (perfectly coalesced).
__global__ __launch_bounds__(256) void prep_kernel(
        const float* __restrict__ inputs, const float* __restrict__ centers,
        unsigned char* __restrict__ Bq, unsigned char* __restrict__ Aq,
        float* __restrict__ x_sq, float* __restrict__ c_sq) {
    const int row  = blockIdx.x * 4 + (threadIdx.x >> 6);
    const int lane = threadIdx.x & 63;
    const bool is_x = row < N_ROWS;
    const int r = is_x ? row : row - N_ROWS;
    const float* src = is_x ? (inputs + (size_t)row * DIM)
                            : (centers + (size_t)r * DIM);
    unsigned char* mat = is_x ? Bq : Aq;
    const float4* s4 = (const float4*)src + lane * 4;
    float s = 0.0f;
    unsigned w[4];
    #pragma unroll
    for (int j = 0; j < 4; ++j) {
        float4 v = s4[j];
        int pk = __builtin_amdgcn_cvt_pk_fp8_f32(v.x, v.y, 0, false);
        pk     = __builtin_amdgcn_cvt_pk_fp8_f32(v.z, v.w, pk, true);
        w[j] = (unsigned)pk;
        s += v.x*v.x + v.y*v.y + v.z*v.z + v.w*v.w;
    }
    const size_t off = (size_t)((r >> 4) * NKB + (lane >> 3)) * TILEB
                     + (r & 15) * 128 + ((lane >> 1) & 3) * 32 + (lane & 1) * 16;
    *(uint4*)(mat + off) = make_uint4(w[0], w[1], w[2], w[3]);
    #pragma unroll
    for (int o = 32; o > 0; o >>= 1) s += __shfl_down(s, o, 64);
    if (lane == 0) {
        if (is_x) x_sq[r] = s;
        else      c_sq[r] = s;
    }
}

// ---- kernel 2: flat MX-fp8 MFMA GEMM — no LDS, no barriers ----
// out[m][n] = 2 * sum_d A[m][d]*B[n][d] - c_sq[m] - x_sq[n]
// 128x128 block tile, 4 waves (each 64x64 via 4x4 of 16x16x128 MFMAs).
// Fragments loaded straight from global (L2-resident, fragment-order layout),
// fully-unrolled ping-pong over the 8 k-blocks.
#define BM 128
#define BN 128

__global__ __launch_bounds__(256, 2) void gemm_kernel(
        const unsigned char* __restrict__ Aq,   // frag-order, 64 x 8 tiles
        const unsigned char* __restrict__ Bq,   // frag-order, 512 x 8 tiles
        const float* __restrict__ x_sq, const float* __restrict__ c_sq,
        float* __restrict__ out) {              // K_CENT x N_ROWS
    const int t    = threadIdx.x;
    const int lane = t & 63;
    const int wave = t >> 6;
    const int wm   = (wave >> 1) * 64;
    const int wn   = (wave & 1) * 64;
    const int m0   = blockIdx.y * BM;
    const int n0   = blockIdx.x * BN;
    const int quad = lane >> 4;
    const int l16  = lane & 15;

    const int laneOff = l16 * 128 + quad * 32;   // 32 B per lane, 32 B aligned
    const unsigned char* pA[4];
    const unsigned char* pB[4];
    #pragma unroll
    for (int i = 0; i < 4; ++i) {
        pA[i] = Aq + (size_t)(((m0 + wm) >> 4) + i) * (NKB * TILEB) + laneOff;
        pB[i] = Bq + (size_t)(((n0 + wn) >> 4) + i) * (NKB * TILEB) + laneOff;
    }

    f32x4 acc[4][4] = {};                        // [mi][ni]
    i32x8 a0[4], b0[4], a1[4], b1[4];

    #pragma unroll
    for (int i = 0; i < 4; ++i) {
        a0[i] = *(const i32x8*)(pA[i]);
        b0[i] = *(const i32x8*)(pB[i]);
    }

    #pragma unroll
    for (int kb = 0; kb < NKB; kb += 2) {
        #pragma unroll
        for (int i = 0; i < 4; ++i) {            // prefetch kb+1
            a1[i] = *(const i32x8*)(pA[i] + (kb + 1) * TILEB);
            b1[i] = *(const i32x8*)(pB[i] + (kb + 1) * TILEB);
        }
        #pragma unroll
        for (int mi = 0; mi < 4; ++mi)
            #pragma unroll
            for (int ni = 0; ni < 4; ++ni)
                acc[mi][ni] = __builtin_amdgcn_mfma_scale_f32_16x16x128_f8f6f4(
                    a0[mi], b0[ni], acc[mi][ni],
                    0, 0, 0, 0x7F7F7F7F, 0, 0x7F7F7F7F);
        if (kb + 2 < NKB) {
            #pragma unroll
            for (int i = 0; i < 4; ++i) {        // prefetch kb+2
                a0[i] = *(const i32x8*)(pA[i] + (kb + 2) * TILEB);
                b0[i] = *(const i32x8*)(pB[i] + (kb + 2) * TILEB);
            }
        }
        #pragma unroll
        for (int mi = 0; mi < 4; ++mi)
            #pragma unroll
            for (int ni = 0; ni < 4; ++ni)
                acc[mi][ni] = __builtin_amdgcn_mfma_scale_f32_16x16x128_f8f6f4(
                    a1[mi], b1[ni], acc[mi][ni],
                    0, 0, 0, 0x7F7F7F7F, 0, 0x7F7F7F7F);
    }

    // epilogue: C/D layout (shape-determined): col(n) = lane&15, row(m) = quad*4 + reg
    #pragma unroll
    for (int ni = 0; ni < 4; ++ni) {
        const int n = n0 + wn + ni * 16 + l16;
        const float xs = x_sq[n];
        #pragma unroll
        for (int mi = 0; mi < 4; ++mi) {
            const int mbase = m0 + wm + mi * 16 + quad * 4;
            #pragma unroll
            for (int r = 0; r < 4; ++r) {
                const int m = mbase + r;
                out[(size_t)m * N_ROWS + n] = 2.0f * acc[mi][ni][r] - c_sq[m] - xs;
            }
        }
    }
}

extern "C" void kernel_launch(void* const* d_in, const int* in_sizes, int n_in,
                              void* d_out, int out_size, void* d_ws, size_t ws_size,
                              hipStream_t stream) {
    const float* inputs  = (const float*)d_in[0];   // (8192, 1024) fp32
    const float* centers = (const float*)d_in[1];   // (1024, 1024) fp32
    float* out = (float*)d_out;                     // (1024, 8192) fp32

    unsigned char* Aq = (unsigned char*)d_ws;            // centers fp8: 1 MB
    unsigned char* Bq = Aq + (size_t)K_CENT * DIM;       // inputs fp8: 8 MB
    float* x_sq = (float*)(Bq + (size_t)N_ROWS * DIM);   // 8192
    float* c_sq = x_sq + N_ROWS;                         // 1024

    prep_kernel<<<(N_ROWS + K_CENT) / 4, 256, 0, stream>>>(
        inputs, centers, Bq, Aq, x_sq, c_sq);
    gemm_kernel<<<dim3(N_ROWS / BN, K_CENT / BM), 256, 0, stream>>>(
        Aq, Bq, x_sq, c_sq, out);
}

// Round 2
// 106.829 us; speedup vs baseline: 1.1087x; 1.1087x over previous
//
#include <hip/hip_runtime.h>

#define N_ROWS 8192   // inputs rows (n)
#define K_CENT 1024   // centers rows (m)
#define DIM    1024   // d (elements; == bytes in fp8)

#define NKB   (DIM / 128)   // 8 k-blocks of 128 fp8 bytes per row
#define TILEB 2048          // bytes per A fragment tile: 16 rows x 128 k

typedef __attribute__((ext_vector_type(4))) float f32x4;
typedef __attribute__((ext_vector_type(8))) int   i32x8;
typedef __attribute__((ext_vector_type(4))) int   i32x4;

__device__ __forceinline__ void async_copy16(const void* g, void* l) {
    __builtin_amdgcn_global_load_lds(
        (const __attribute__((address_space(1))) unsigned int*)g,
        (__attribute__((address_space(3))) unsigned int*)l,
        16, 0, 0);
}

// ---- kernel 1: fp32 -> fp8 e4m3 (scale 2^0) + fp32-exact row norms ----
// one wave per row; lane handles 16 contiguous elems (64 B read, 16 B write).
// Bq (inputs): linear row-major (round-0 layout, staged via LDS in gemm).
// Aq (centers): MFMA fragment-order — tile (r>>4, kb) of 2048 B, within tile
//   row (r&15)*128 + quad*32 + half*16, so a gemm wave reads contiguous 2 KB.
__global__ __launch_bounds__(256) void prep_kernel(
        const float* __restrict__ inputs, const float* __restrict__ centers,
        unsigned char* __restrict__ Bq, unsigned char* __restrict__ Aq,
        float* __restrict__ x_sq, float* __restrict__ c_sq) {
    const int row  = blockIdx.x * 4 + (threadIdx.x >> 6);
    const int lane = threadIdx.x & 63;
    const bool is_x = row < N_ROWS;
    const int r = is_x ? row : row - N_ROWS;
    const float* src = is_x ? (inputs + (size_t)row * DIM)
                            : (centers + (size_t)r * DIM);
    const float4* s4 = (const float4*)src + lane * 4;
    float s = 0.0f;
    unsigned w[4];
    #pragma unroll
    for (int j = 0; j < 4; ++j) {
        float4 v = s4[j];
        int pk = __builtin_amdgcn_cvt_pk_fp8_f32(v.x, v.y, 0, false);
        pk     = __builtin_amdgcn_cvt_pk_fp8_f32(v.z, v.w, pk, true);
        w[j] = (unsigned)pk;
        s += v.x*v.x + v.y*v.y + v.z*v.z + v.w*v.w;
    }
    if (is_x) {
        *(uint4*)(Bq + (size_t)r * DIM + lane * 16) = make_uint4(w[0], w[1], w[2], w[3]);
    } else {
        // k = lane*16..+15: kb = lane>>3, quad = (lane>>1)&3, half = lane&1
        const size_t off = (size_t)((r >> 4) * NKB + (lane >> 3)) * TILEB
                         + (r & 15) * 128 + ((lane >> 1) & 3) * 32 + (lane & 1) * 16;
        *(uint4*)(Aq + off) = make_uint4(w[0], w[1], w[2], w[3]);
    }
    #pragma unroll
    for (int o = 32; o > 0; o >>= 1) s += __shfl_down(s, o, 64);
    if (lane == 0) {
        if (is_x) x_sq[r] = s;
        else      c_sq[r] = s;
    }
}

// ---- kernel 2: MX-fp8 MFMA GEMM — B via dbuf LDS (round-0 path), A direct ----
// out[m][n] = 2 * sum_d A[m][d]*B[n][d] - c_sq[m] - x_sq[n]
// 128x128 tile, 4 waves (each 64x64 via 4x4 of 16x16x128 MFMAs), BK=128.
// A fragments stream straight from L2 (fragment-order, read exactly once),
// one-iteration register ping-pong. LDS traffic per iter halves vs round-0.
#define BM 128
#define BN 128
#define BK 128
#define NITER (DIM / BK)

__device__ __forceinline__ i32x8 read_frag(const unsigned char* base, int rowByte,
                                           int off1, int off2) {
    i32x4 lo = *(const i32x4*)(base + rowByte + off1);
    i32x4 hi = *(const i32x4*)(base + rowByte + off2);
    i32x8 f;
    f[0]=lo[0]; f[1]=lo[1]; f[2]=lo[2]; f[3]=lo[3];
    f[4]=hi[0]; f[5]=hi[1]; f[6]=hi[2]; f[7]=hi[3];
    return f;
}

__global__ __launch_bounds__(256, 2) void gemm_kernel(
        const unsigned char* __restrict__ Aq,   // frag-order: 64 x 8 tiles of 2 KB
        const unsigned char* __restrict__ Bq,   // linear: N_ROWS x DIM fp8
        const float* __restrict__ x_sq, const float* __restrict__ c_sq,
        float* __restrict__ out) {              // K_CENT x N_ROWS
    __shared__ unsigned char sB[2][BN * BK];    // 2 x 16 KB

    const int t    = threadIdx.x;
    const int lane = t & 63;
    const int wave = t >> 6;
    const int wm   = (wave >> 1) * 64;
    const int wn   = (wave & 1) * 64;
    const int m0   = blockIdx.y * BM;
    const int n0   = blockIdx.x * BN;
    const int quad = lane >> 4;
    const int l16  = lane & 15;

    // B staging: 1024 16-B units per iter; 4 per thread; XOR-swizzled rows
    const unsigned char* gB[4];
    int ldsOff[4];
    #pragma unroll
    for (int i = 0; i < 4; ++i) {
        const int p = i * 256 + t;          // phys unit index
        const int r = p >> 3;               // row 0..127
        const int h = (p & 7) ^ (r & 7);    // logical 16-B unit in row
        gB[i] = Bq + (size_t)(n0 + r) * DIM + h * 16;
        ldsOff[i] = p * 16;
    }

    // B fragment phys offsets (XOR layout)
    const int off1 = (((quad << 1)    ) ^ (l16 & 7)) << 4;
    const int off2 = (((quad << 1) | 1) ^ (l16 & 7)) << 4;

    // A direct pointers: wave reads contiguous 2 KB tile per (mi, kb)
    const unsigned char* pA[4];
    #pragma unroll
    for (int mi = 0; mi < 4; ++mi)
        pA[mi] = Aq + (size_t)(((m0 + wm) >> 4) + mi) * (NKB * TILEB)
               + l16 * 128 + quad * 32;

    f32x4 acc[4][4] = {};                   // [mi][ni]
    i32x8 aCur[4], aNxt[4];

    #pragma unroll
    for (int i = 0; i < 4; ++i)
        async_copy16(gB[i], &sB[0][ldsOff[i]]);
    #pragma unroll
    for (int mi = 0; mi < 4; ++mi)
        aCur[mi] = *(const i32x8*)(pA[mi]);

    #pragma unroll
    for (int it = 0; it < NITER; ++it) {
        __syncthreads();                    // publishes B buf it&1

        if (it + 1 < NITER) {
            const int nb = (it + 1) & 1;
            const int koff = (it + 1) * BK;
            #pragma unroll
            for (int i = 0; i < 4; ++i)
                async_copy16(gB[i] + koff, &sB[nb][ldsOff[i]]);
            #pragma unroll
            for (int mi = 0; mi < 4; ++mi)
                aNxt[mi] = *(const i32x8*)(pA[mi] + (it + 1) * TILEB);
        }

        const unsigned char* B = sB[it & 1];
        i32x8 bf[4];
        #pragma unroll
        for (int ni = 0; ni < 4; ++ni)
            bf[ni] = read_frag(B, (wn + ni * 16 + l16) << 7, off1, off2);
        #pragma unroll
        for (int mi = 0; mi < 4; ++mi)
            #pragma unroll
            for (int ni = 0; ni < 4; ++ni)
                acc[mi][ni] = __builtin_amdgcn_mfma_scale_f32_16x16x128_f8f6f4(
                    aCur[mi], bf[ni], acc[mi][ni],
                    0, 0,                    // cbsz=fp8(e4m3), blgp=fp8(e4m3)
                    0, 0x7F7F7F7F,           // scale_a = 2^0
                    0, 0x7F7F7F7F);          // scale_b = 2^0
        #pragma unroll
        for (int mi = 0; mi < 4; ++mi)
            aCur[mi] = aNxt[mi];            // fully unrolled -> register rename
    }

    // epilogue: C/D layout (shape-determined): col(n) = lane&15, row(m) = quad*4 + reg
    #pragma unroll
    for (int ni = 0; ni < 4; ++ni) {
        const int n = n0 + wn + ni * 16 + l16;
        const float xs = x_sq[n];
        #pragma unroll
        for (int mi = 0; mi < 4; ++mi) {
            const int mbase = m0 + wm + mi * 16 + quad * 4;
            #pragma unroll
            for (int r = 0; r < 4; ++r) {
                const int m = mbase + r;
                out[(size_t)m * N_ROWS + n] = 2.0f * acc[mi][ni][r] - c_sq[m] - xs;
            }
        }
    }
}

extern "C" void kernel_launch(void* const* d_in, const int* in_sizes, int n_in,
                              void* d_out, int out_size, void* d_ws, size_t ws_size,
                              hipStream_t stream) {
    const float* inputs  = (const float*)d_in[0];   // (8192, 1024) fp32
    const float* centers = (const float*)d_in[1];   // (1024, 1024) fp32
    float* out = (float*)d_out;                     // (1024, 8192) fp32

    unsigned char* Aq = (unsigned char*)d_ws;            // centers fp8 frag-order: 1 MB
    unsigned char* Bq = Aq + (size_t)K_CENT * DIM;       // inputs fp8 linear: 8 MB
    float* x_sq = (float*)(Bq + (size_t)N_ROWS * DIM);   // 8192
    float* c_sq = x_sq + N_ROWS;                         // 1024

    prep_kernel<<<(N_ROWS + K_CENT) / 4, 256, 0, stream>>>(
        inputs, centers, Bq, Aq, x_sq, c_sq);
    gemm_kernel<<<dim3(N_ROWS / BN, K_CENT / BM), 256, 0, stream>>>(
        Aq, Bq, x_sq, c_sq, out);
}